// Round 3
// baseline (227.208 us; speedup 1.0000x reference)
//
#include <hip/hip_runtime.h>

// Sparsemax over last dim, rows of N=512 fp32.
// One 64-lane wave per row; 8 elements/lane in registers.
// tau via Michelot fixed-point (== Newton on the piecewise-linear simplex
// projection equation; finite convergence, support shrinks monotonically).
// VALU diet: support COUNT via ballot + scalar popcount (scalar pipe),
// division via v_rcp_f32, no max-shift (tau is shift-invariant; fp32-safe
// at these magnitudes), single DPP reduction chain per iteration.

#define ROW_N 512
#define LANES 64
#define EPL 8  // elements per lane

// One DPP step: v = v + dpp_move(v). bound_ctrl=1 -> OOB lanes read 0.
#define DPP_ADD_STEP(v, ctrl, rmask)                                        \
  v += __int_as_float(__builtin_amdgcn_update_dpp(                          \
      0, __float_as_int(v), ctrl, rmask, 0xf, true))

// Full-wave (64-lane) sum; result uniform via readlane -> sgpr broadcast.
__device__ inline float wave_sum64(float v) {
  DPP_ADD_STEP(v, 0x111, 0xf);  // row_shr:1
  DPP_ADD_STEP(v, 0x112, 0xf);  // row_shr:2
  DPP_ADD_STEP(v, 0x114, 0xf);  // row_shr:4
  DPP_ADD_STEP(v, 0x118, 0xf);  // row_shr:8  -> lane15 of each 16-row = sum
  DPP_ADD_STEP(v, 0x142, 0xa);  // row_bcast:15 -> lanes 31, 63
  DPP_ADD_STEP(v, 0x143, 0xc);  // row_bcast:31 -> lane 63 = wave total
  return __int_as_float(__builtin_amdgcn_readlane(__float_as_int(v), 63));
}

__global__ __launch_bounds__(256) void sparsemax_kernel(
    const float* __restrict__ x, float* __restrict__ out, int nrows) {
  const int lane = threadIdx.x & 63;
  const int wave = threadIdx.x >> 6;
  const int row = blockIdx.x * 4 + wave;
  if (row >= nrows) return;

  const float4* xr = (const float4*)(x + (size_t)row * ROW_N);
  float4* outr = (float4*)(out + (size_t)row * ROW_N);

  float4 a = xr[lane];
  float4 b = xr[lane + LANES];
  float z[EPL] = {a.x, a.y, a.z, a.w, b.x, b.y, b.z, b.w};

  // Initial tau with full support. (No max-shift: tau and the output are
  // shift-invariant; fp32 sums of 512 N(0,1) values are well-conditioned.)
  float s = 0.0f;
#pragma unroll
  for (int i = 0; i < EPL; ++i) s += z[i];
  s = wave_sum64(s);
  float tau = (s - 1.0f) * (1.0f / (float)ROW_N);  // exact *2^-9

  // Michelot loop. Support shrinks monotonically; same count => same set.
  int prev_k = ROW_N;
  for (int iter = 0; iter < 32; ++iter) {
    float ls = 0.0f;
    int k = 0;
#pragma unroll
    for (int i = 0; i < EPL; ++i) {
      bool g = z[i] > tau;
      ls += g ? z[i] : 0.0f;                    // VALU: cmp + cndmask + add
      k += (int)__popcll(__ballot(g));          // scalar pipe: s_bcnt1 + s_add
    }
    ls = wave_sum64(ls);
    tau = (ls - 1.0f) * __builtin_amdgcn_rcpf((float)k);  // 1-ulp rcp
    if (k == prev_k) break;  // support stable -> tau is the fixed point
    prev_k = k;
  }

  float4 oa = {fmaxf(z[0] - tau, 0.0f), fmaxf(z[1] - tau, 0.0f),
               fmaxf(z[2] - tau, 0.0f), fmaxf(z[3] - tau, 0.0f)};
  float4 ob = {fmaxf(z[4] - tau, 0.0f), fmaxf(z[5] - tau, 0.0f),
               fmaxf(z[6] - tau, 0.0f), fmaxf(z[7] - tau, 0.0f)};
  outr[lane] = oa;
  outr[lane + LANES] = ob;
}

extern "C" void kernel_launch(void* const* d_in, const int* in_sizes, int n_in,
                              void* d_out, int out_size, void* d_ws,
                              size_t ws_size, hipStream_t stream) {
  const float* x = (const float*)d_in[0];
  float* out = (float*)d_out;
  const int nrows = in_sizes[0] / ROW_N;
  const int blocks = (nrows + 3) / 4;
  sparsemax_kernel<<<blocks, 256, 0, stream>>>(x, out, nrows);
}